// Round 11
// baseline (616.503 us; speedup 1.0000x reference)
//
#include <hip/hip_runtime.h>
#include <math.h>

typedef unsigned int uint;
typedef unsigned short ushort;
using bf8   = __attribute__((ext_vector_type(8))) short;   // 8 bf16 (4 VGPRs)
using f32x4 = __attribute__((ext_vector_type(4))) float;   // 4 fp32

__device__ inline ushort f2bf(float f) {
  uint u = __float_as_uint(f);
  return (ushort)((u + 0x7fffu + ((u >> 16) & 1u)) >> 16);
}
__device__ inline float bf2f(ushort s) { return __uint_as_float(((uint)s) << 16); }
__device__ inline uint packbf2(float a, float b) {
  uint ua = __float_as_uint(a), ub = __float_as_uint(b);
  ua = (ua + 0x7fffu + ((ua >> 16) & 1u)) >> 16;
  ub = (ub + 0x7fffu + ((ub >> 16) & 1u)) & 0xffff0000u;
  return ua | ub;
}
__device__ inline float bflo(uint u) { return __uint_as_float(u << 16); }
__device__ inline float bfhi(uint u) { return __uint_as_float(u & 0xffff0000u); }

// ---------------- CSR build ----------------
__global__ void hist_k(const int* __restrict__ dst, int* __restrict__ cnt, int E) {
  int tid = blockIdx.x * blockDim.x + threadIdx.x;
  int stride4 = gridDim.x * blockDim.x * 4;
  for (int base = tid * 4; base + 3 < E; base += stride4) {
    int4 d = *(const int4*)&dst[base];
    atomicAdd(&cnt[d.x], 1);
    atomicAdd(&cnt[d.y], 1);
    atomicAdd(&cnt[d.z], 1);
    atomicAdd(&cnt[d.w], 1);
  }
  int tail0 = (E & ~3);
  int e = tail0 + tid;
  if (e < E) atomicAdd(&cnt[dst[e]], 1);
}

__global__ __launch_bounds__(256) void scanA_k(const int* __restrict__ cnt,
                                               int* __restrict__ bsum, int N) {
  __shared__ int red[256];
  int tid = threadIdx.x;
  int i0 = blockIdx.x * 1024 + tid * 4;
  int s = 0;
  #pragma unroll
  for (int k = 0; k < 4; ++k) { int i = i0 + k; if (i < N) s += cnt[i]; }
  red[tid] = s;
  __syncthreads();
  for (int off = 128; off; off >>= 1) {
    if (tid < off) red[tid] += red[tid + off];
    __syncthreads();
  }
  if (tid == 0) bsum[blockIdx.x] = red[0];
}

__global__ __launch_bounds__(128) void scanB_k(const int* __restrict__ bsum,
                                               int* __restrict__ bbase, int nb) {
  __shared__ int buf[2][128];
  int tid = threadIdx.x;
  buf[0][tid] = (tid < nb) ? bsum[tid] : 0;
  __syncthreads();
  int pin = 0;
  for (int off = 1; off < 128; off <<= 1) {
    int x = buf[pin][tid];
    if (tid >= off) x += buf[pin][tid - off];
    buf[1 - pin][tid] = x;
    __syncthreads();
    pin = 1 - pin;
  }
  if (tid < nb) bbase[tid] = (tid == 0) ? 0 : buf[pin][tid - 1];
}

__global__ __launch_bounds__(256) void scanC_k(const int* __restrict__ cnt,
    const int* __restrict__ bbase, int* __restrict__ rp, int N, int E) {
  __shared__ int buf[2][256];
  int tid = threadIdx.x;
  int i0 = blockIdx.x * 1024 + tid * 4;
  int c[4]; int s = 0;
  #pragma unroll
  for (int k = 0; k < 4; ++k) { int i = i0 + k; c[k] = (i < N) ? cnt[i] : 0; s += c[k]; }
  buf[0][tid] = s;
  __syncthreads();
  int pin = 0;
  for (int off = 1; off < 256; off <<= 1) {
    int x = buf[pin][tid];
    if (tid >= off) x += buf[pin][tid - off];
    buf[1 - pin][tid] = x;
    __syncthreads();
    pin = 1 - pin;
  }
  int run = bbase[blockIdx.x] + buf[pin][tid] - s;
  #pragma unroll
  for (int k = 0; k < 4; ++k) {
    int i = i0 + k;
    if (i < N) { rp[i] = run; run += c[k]; }
  }
  if (blockIdx.x == 0 && tid == 0) rp[N] = E;
}

// scatter into per-node CSR slots; consumes hist counts via atomic decrement
__global__ void scatter_k(const int* __restrict__ src, const int* __restrict__ dst,
                          const float* __restrict__ w, const int* __restrict__ rp,
                          int* __restrict__ cnt, int2* __restrict__ epk, int E) {
  int stride = gridDim.x * blockDim.x;
  for (int e = blockIdx.x * blockDim.x + threadIdx.x; e < E; e += stride) {
    int d = dst[e];
    int off = atomicAdd(&cnt[d], -1) - 1;
    epk[rp[d] + off] = make_int2(src[e], __float_as_int(w[e]));
  }
}

// ---- prep: transpose + bf16-convert all 6 weight matrices to Wt[m][n][k] ----
// block b: matrix m = b>>4, rows n0..n0+7. Reads W[k][n] (f32, L2-resident),
// writes contiguous bf16 runs (coalesced 256B per 32-lane group).
__global__ __launch_bounds__(256) void prepW_k(const float* __restrict__ W0,
    const float* __restrict__ convW, const float* __restrict__ W1,
    ushort* __restrict__ Wt) {
  int b = blockIdx.x;
  int m = b >> 4;
  int n0 = (b & 15) * 8;
  const float* W = (m == 0) ? W0 : (m <= 4) ? (convW + (size_t)(m - 1) * 128 * 128) : W1;
  ushort* dst = Wt + (size_t)m * 128 * 128;
  int t = threadIdx.x;
  int n = n0 + (t >> 5);
  int k0 = (t & 31) * 4;
  float a = W[(size_t)(k0 + 0) * 128 + n];
  float c = W[(size_t)(k0 + 1) * 128 + n];
  float d = W[(size_t)(k0 + 2) * 128 + n];
  float e = W[(size_t)(k0 + 3) * 128 + n];
  *(uint2*)&dst[(size_t)n * 128 + k0] = make_uint2(packbf2(a, c), packbf2(d, e));
}

// ---------------- SpMM (pull, CSR by dst, bf16 gather) + initial-residual mix ----------------
// One node per 16-lane group; 8-deep unroll (throughput-bound; kept for free ILP).
__global__ __launch_bounds__(256) void spmm_k(const int* __restrict__ rp,
    const int2* __restrict__ epk, const ushort* __restrict__ hbf,
    const ushort* __restrict__ x0bf, ushort* __restrict__ outbf, int N) {
  int node = (blockIdx.x * blockDim.x + threadIdx.x) >> 4;
  int l16 = threadIdx.x & 15;
  if (node >= N) return;
  int b = rp[node], e = rp[node + 1];
  float a0 = 0.f, a1 = 0.f, a2 = 0.f, a3 = 0.f;
  float a4 = 0.f, a5 = 0.f, a6 = 0.f, a7 = 0.f;
  const uint4* hb4 = (const uint4*)hbf;
  int j = b;
  for (; j + 7 < e; j += 8) {
    int2 e0 = epk[j],     e1 = epk[j + 1], e2 = epk[j + 2], e3 = epk[j + 3];
    int2 e4 = epk[j + 4], e5 = epk[j + 5], e6 = epk[j + 6], e7 = epk[j + 7];
    uint4 h0 = hb4[(size_t)e0.x * 16 + l16];
    uint4 h1 = hb4[(size_t)e1.x * 16 + l16];
    uint4 h2 = hb4[(size_t)e2.x * 16 + l16];
    uint4 h3 = hb4[(size_t)e3.x * 16 + l16];
    uint4 h4 = hb4[(size_t)e4.x * 16 + l16];
    uint4 h5 = hb4[(size_t)e5.x * 16 + l16];
    uint4 h6 = hb4[(size_t)e6.x * 16 + l16];
    uint4 h7 = hb4[(size_t)e7.x * 16 + l16];
    float w0 = __int_as_float(e0.y), w1 = __int_as_float(e1.y);
    float w2 = __int_as_float(e2.y), w3 = __int_as_float(e3.y);
    float w4 = __int_as_float(e4.y), w5 = __int_as_float(e5.y);
    float w6 = __int_as_float(e6.y), w7 = __int_as_float(e7.y);
    a0 = fmaf(w0, bflo(h0.x), a0); a1 = fmaf(w0, bfhi(h0.x), a1);
    a2 = fmaf(w0, bflo(h0.y), a2); a3 = fmaf(w0, bfhi(h0.y), a3);
    a4 = fmaf(w0, bflo(h0.z), a4); a5 = fmaf(w0, bfhi(h0.z), a5);
    a6 = fmaf(w0, bflo(h0.w), a6); a7 = fmaf(w0, bfhi(h0.w), a7);
    a0 = fmaf(w1, bflo(h1.x), a0); a1 = fmaf(w1, bfhi(h1.x), a1);
    a2 = fmaf(w1, bflo(h1.y), a2); a3 = fmaf(w1, bfhi(h1.y), a3);
    a4 = fmaf(w1, bflo(h1.z), a4); a5 = fmaf(w1, bfhi(h1.z), a5);
    a6 = fmaf(w1, bflo(h1.w), a6); a7 = fmaf(w1, bfhi(h1.w), a7);
    a0 = fmaf(w2, bflo(h2.x), a0); a1 = fmaf(w2, bfhi(h2.x), a1);
    a2 = fmaf(w2, bflo(h2.y), a2); a3 = fmaf(w2, bfhi(h2.y), a3);
    a4 = fmaf(w2, bflo(h2.z), a4); a5 = fmaf(w2, bfhi(h2.z), a5);
    a6 = fmaf(w2, bflo(h2.w), a6); a7 = fmaf(w2, bfhi(h2.w), a7);
    a0 = fmaf(w3, bflo(h3.x), a0); a1 = fmaf(w3, bfhi(h3.x), a1);
    a2 = fmaf(w3, bflo(h3.y), a2); a3 = fmaf(w3, bfhi(h3.y), a3);
    a4 = fmaf(w3, bflo(h3.z), a4); a5 = fmaf(w3, bfhi(h3.z), a5);
    a6 = fmaf(w3, bflo(h3.w), a6); a7 = fmaf(w3, bfhi(h3.w), a7);
    a0 = fmaf(w4, bflo(h4.x), a0); a1 = fmaf(w4, bfhi(h4.x), a1);
    a2 = fmaf(w4, bflo(h4.y), a2); a3 = fmaf(w4, bfhi(h4.y), a3);
    a4 = fmaf(w4, bflo(h4.z), a4); a5 = fmaf(w4, bfhi(h4.z), a5);
    a6 = fmaf(w4, bflo(h4.w), a6); a7 = fmaf(w4, bfhi(h4.w), a7);
    a0 = fmaf(w5, bflo(h5.x), a0); a1 = fmaf(w5, bfhi(h5.x), a1);
    a2 = fmaf(w5, bflo(h5.y), a2); a3 = fmaf(w5, bfhi(h5.y), a3);
    a4 = fmaf(w5, bflo(h5.z), a4); a5 = fmaf(w5, bfhi(h5.z), a5);
    a6 = fmaf(w5, bflo(h5.w), a6); a7 = fmaf(w5, bfhi(h5.w), a7);
    a0 = fmaf(w6, bflo(h6.x), a0); a1 = fmaf(w6, bfhi(h6.x), a1);
    a2 = fmaf(w6, bflo(h6.y), a2); a3 = fmaf(w6, bfhi(h6.y), a3);
    a4 = fmaf(w6, bflo(h6.z), a4); a5 = fmaf(w6, bfhi(h6.z), a5);
    a6 = fmaf(w6, bflo(h6.w), a6); a7 = fmaf(w6, bfhi(h6.w), a7);
    a0 = fmaf(w7, bflo(h7.x), a0); a1 = fmaf(w7, bfhi(h7.x), a1);
    a2 = fmaf(w7, bflo(h7.y), a2); a3 = fmaf(w7, bfhi(h7.y), a3);
    a4 = fmaf(w7, bflo(h7.z), a4); a5 = fmaf(w7, bfhi(h7.z), a5);
    a6 = fmaf(w7, bflo(h7.w), a6); a7 = fmaf(w7, bfhi(h7.w), a7);
  }
  for (; j + 3 < e; j += 4) {
    int2 e0 = epk[j], e1 = epk[j + 1], e2 = epk[j + 2], e3 = epk[j + 3];
    uint4 h0 = hb4[(size_t)e0.x * 16 + l16];
    uint4 h1 = hb4[(size_t)e1.x * 16 + l16];
    uint4 h2 = hb4[(size_t)e2.x * 16 + l16];
    uint4 h3 = hb4[(size_t)e3.x * 16 + l16];
    float w0 = __int_as_float(e0.y), w1 = __int_as_float(e1.y);
    float w2 = __int_as_float(e2.y), w3 = __int_as_float(e3.y);
    a0 = fmaf(w0, bflo(h0.x), a0); a1 = fmaf(w0, bfhi(h0.x), a1);
    a2 = fmaf(w0, bflo(h0.y), a2); a3 = fmaf(w0, bfhi(h0.y), a3);
    a4 = fmaf(w0, bflo(h0.z), a4); a5 = fmaf(w0, bfhi(h0.z), a5);
    a6 = fmaf(w0, bflo(h0.w), a6); a7 = fmaf(w0, bfhi(h0.w), a7);
    a0 = fmaf(w1, bflo(h1.x), a0); a1 = fmaf(w1, bfhi(h1.x), a1);
    a2 = fmaf(w1, bflo(h1.y), a2); a3 = fmaf(w1, bfhi(h1.y), a3);
    a4 = fmaf(w1, bflo(h1.z), a4); a5 = fmaf(w1, bfhi(h1.z), a5);
    a6 = fmaf(w1, bflo(h1.w), a6); a7 = fmaf(w1, bfhi(h1.w), a7);
    a0 = fmaf(w2, bflo(h2.x), a0); a1 = fmaf(w2, bfhi(h2.x), a1);
    a2 = fmaf(w2, bflo(h2.y), a2); a3 = fmaf(w2, bfhi(h2.y), a3);
    a4 = fmaf(w2, bflo(h2.z), a4); a5 = fmaf(w2, bfhi(h2.z), a5);
    a6 = fmaf(w2, bflo(h2.w), a6); a7 = fmaf(w2, bfhi(h2.w), a7);
    a0 = fmaf(w3, bflo(h3.x), a0); a1 = fmaf(w3, bfhi(h3.x), a1);
    a2 = fmaf(w3, bflo(h3.y), a2); a3 = fmaf(w3, bfhi(h3.y), a3);
    a4 = fmaf(w3, bflo(h3.z), a4); a5 = fmaf(w3, bfhi(h3.z), a5);
    a6 = fmaf(w3, bflo(h3.w), a6); a7 = fmaf(w3, bfhi(h3.w), a7);
  }
  for (; j < e; ++j) {
    int2 e0 = epk[j];
    float w0 = __int_as_float(e0.y);
    uint4 h0 = hb4[(size_t)e0.x * 16 + l16];
    a0 = fmaf(w0, bflo(h0.x), a0); a1 = fmaf(w0, bfhi(h0.x), a1);
    a2 = fmaf(w0, bflo(h0.y), a2); a3 = fmaf(w0, bfhi(h0.y), a3);
    a4 = fmaf(w0, bflo(h0.z), a4); a5 = fmaf(w0, bfhi(h0.z), a5);
    a6 = fmaf(w0, bflo(h0.w), a6); a7 = fmaf(w0, bfhi(h0.w), a7);
  }
  uint4 xv = ((const uint4*)x0bf)[(size_t)node * 16 + l16];
  float o0 = 0.9f * a0 + 0.1f * bflo(xv.x);
  float o1 = 0.9f * a1 + 0.1f * bfhi(xv.x);
  float o2 = 0.9f * a2 + 0.1f * bflo(xv.y);
  float o3 = 0.9f * a3 + 0.1f * bfhi(xv.y);
  float o4 = 0.9f * a4 + 0.1f * bflo(xv.z);
  float o5 = 0.9f * a5 + 0.1f * bfhi(xv.z);
  float o6 = 0.9f * a6 + 0.1f * bflo(xv.w);
  float o7 = 0.9f * a7 + 0.1f * bfhi(xv.w);
  uint4 u;
  u.x = packbf2(o0, o1); u.y = packbf2(o2, o3);
  u.z = packbf2(o4, o5); u.w = packbf2(o6, o7);
  ((uint4*)outbf)[(size_t)node * 16 + l16] = u;
}

// ---------------- MFMA dense GEMM, LDS-free ----------------
// 128 rows/block, 4 waves x 32 rows; per wave 2 row-tiles x 8 col-tiles of
// 16x16, K-steps of 32. A and B fragments both load direct from global
// (validated mapping: fragment index = lane&15, k = kt*32 + 8*(lane>>4)+j).
// B source: Wt bf16 [n][k] (pre-transposed by prepW_k; 32KB, L1/L2-resident).
// D layout: col = lane&15, row = 4*(lane>>4) + reg.
// MODE 0 (proj, ABF=0): y = relu(in@W + bias); bf16 -> outbf (h), outbf2 (x0)
// MODE 1 (conv, ABF=1): y = relu(cin*in + cw*(in@W)); bf16 -> outbf
// MODE 2 (final,ABF=1): y = log_softmax(in@W + bias); f32 -> outf
template<int MODE, int ABF>
__global__ __launch_bounds__(256, 4) void gemm_mfma(const void* __restrict__ inv,
    const ushort* __restrict__ Wt, const float* __restrict__ bias,
    float* __restrict__ outf, ushort* __restrict__ outbf, ushort* __restrict__ outbf2,
    float cin, float cw, int N) {
  const float*  inf = (const float*)inv;
  const ushort* inb = (const ushort*)inv;
  int tid = threadIdx.x;
  int w = tid >> 6, lane = tid & 63;
  int l15 = lane & 15, hi = lane >> 4;
  int rbase = blockIdx.x * 128 + w * 32;

  f32x4 acc[2][8];
  #pragma unroll
  for (int mi = 0; mi < 2; ++mi)
    #pragma unroll
    for (int ni = 0; ni < 8; ++ni)
      acc[mi][ni] = (f32x4){0.f, 0.f, 0.f, 0.f};

  int r0 = min(rbase + l15, N - 1);
  int r1 = min(rbase + 16 + l15, N - 1);

  #pragma unroll
  for (int kt = 0; kt < 4; ++kt) {
    int koff = kt * 32 + hi * 8;
    bf8 a0, a1;
    if (ABF) {
      a0 = *(const bf8*)&inb[(size_t)r0 * 128 + koff];
      a1 = *(const bf8*)&inb[(size_t)r1 * 128 + koff];
    } else {
      float4 f0 = *(const float4*)&inf[(size_t)r0 * 128 + koff];
      float4 f1 = *(const float4*)&inf[(size_t)r0 * 128 + koff + 4];
      float4 g0 = *(const float4*)&inf[(size_t)r1 * 128 + koff];
      float4 g1 = *(const float4*)&inf[(size_t)r1 * 128 + koff + 4];
      union { bf8 v; uint u[4]; } ta, tb;
      ta.u[0] = packbf2(f0.x, f0.y); ta.u[1] = packbf2(f0.z, f0.w);
      ta.u[2] = packbf2(f1.x, f1.y); ta.u[3] = packbf2(f1.z, f1.w);
      tb.u[0] = packbf2(g0.x, g0.y); tb.u[1] = packbf2(g0.z, g0.w);
      tb.u[2] = packbf2(g1.x, g1.y); tb.u[3] = packbf2(g1.z, g1.w);
      a0 = ta.v; a1 = tb.v;
    }
    #pragma unroll
    for (int ni = 0; ni < 8; ++ni) {
      bf8 b = *(const bf8*)&Wt[(size_t)(ni * 16 + l15) * 128 + koff];
      acc[0][ni] = __builtin_amdgcn_mfma_f32_16x16x32_bf16(a0, b, acc[0][ni], 0, 0, 0);
      acc[1][ni] = __builtin_amdgcn_mfma_f32_16x16x32_bf16(a1, b, acc[1][ni], 0, 0, 0);
    }
  }

  float bcol[8];
  if (MODE != 1) {
    #pragma unroll
    for (int ni = 0; ni < 8; ++ni) bcol[ni] = bias[ni * 16 + l15];
  }

  #pragma unroll
  for (int mi = 0; mi < 2; ++mi) {
    #pragma unroll
    for (int reg = 0; reg < 4; ++reg) {
      int row = rbase + mi * 16 + 4 * hi + reg;
      bool valid = (row < N);
      float y[8];
      #pragma unroll
      for (int ni = 0; ni < 8; ++ni) y[ni] = acc[mi][ni][reg];
      if (MODE == 1) {
        if (valid) {
          #pragma unroll
          for (int ni = 0; ni < 8; ++ni) {
            float iv = bf2f(inb[(size_t)row * 128 + ni * 16 + l15]);
            y[ni] = fmaxf(cin * iv + cw * y[ni], 0.f);
          }
        }
      } else {
        #pragma unroll
        for (int ni = 0; ni < 8; ++ni) y[ni] += bcol[ni];
        if (MODE == 0) {
          #pragma unroll
          for (int ni = 0; ni < 8; ++ni) y[ni] = fmaxf(y[ni], 0.f);
        }
      }
      if (MODE == 2) {
        float m = y[0];
        #pragma unroll
        for (int ni = 1; ni < 8; ++ni) m = fmaxf(m, y[ni]);
        #pragma unroll
        for (int off = 1; off <= 8; off <<= 1) m = fmaxf(m, __shfl_xor(m, off));
        float s = 0.f;
        #pragma unroll
        for (int ni = 0; ni < 8; ++ni) s += expf(y[ni] - m);
        #pragma unroll
        for (int off = 1; off <= 8; off <<= 1) s += __shfl_xor(s, off);
        float lg = m + logf(s);
        #pragma unroll
        for (int ni = 0; ni < 8; ++ni) y[ni] -= lg;
      }
      if (valid) {
        if (MODE == 2) {
          #pragma unroll
          for (int ni = 0; ni < 8; ++ni)
            outf[(size_t)row * 128 + ni * 16 + l15] = y[ni];
        } else {
          #pragma unroll
          for (int ni = 0; ni < 8; ++ni) {
            ushort u = f2bf(y[ni]);
            outbf[(size_t)row * 128 + ni * 16 + l15] = u;
            if (MODE == 0) outbf2[(size_t)row * 128 + ni * 16 + l15] = u;
          }
        }
      }
    }
  }
}

extern "C" void kernel_launch(void* const* d_in, const int* in_sizes, int n_in,
                              void* d_out, int out_size, void* d_ws, size_t ws_size,
                              hipStream_t stream) {
  const float* x     = (const float*)d_in[0];
  const int*   esrc  = (const int*)d_in[1];
  const int*   edst  = (const int*)d_in[2];
  const float* ew    = (const float*)d_in[3];
  const float* W0    = (const float*)d_in[4];
  const float* b0    = (const float*)d_in[5];
  const float* W1    = (const float*)d_in[6];
  const float* b1    = (const float*)d_in[7];
  const float* convW = (const float*)d_in[8];
  int N = in_sizes[0] / 128;
  int E = in_sizes[1];
  float* outp = (float*)d_out;

  char* ws = (char*)d_ws;
  size_t off = 0;
  auto alloc = [&](size_t bytes) {
    void* p = ws + off;
    off += (bytes + 255) & ~(size_t)255;
    return p;
  };
  ushort* hbf   = (ushort*)alloc((size_t)N * 128 * 2);
  ushort* x0bf  = (ushort*)alloc((size_t)N * 128 * 2);
  ushort* bufB  = (ushort*)alloc((size_t)N * 128 * 2);   // spmm out (bf16)
  ushort* bufA  = (ushort*)alloc((size_t)N * 128 * 2);   // final-GEMM input (bf16)
  ushort* Wtg   = (ushort*)alloc((size_t)6 * 128 * 128 * 2);
  int*    rp    = (int*)alloc((size_t)(N + 1) * 4);
  int*    cnt   = (int*)alloc((size_t)N * 4);
  int2*   epk   = (int2*)alloc((size_t)E * 8);
  int nbScan = (N + 1023) / 1024;
  int*    bsum  = (int*)alloc((size_t)nbScan * 4);
  int*    bbase = (int*)alloc((size_t)nbScan * 4);

  // ---- CSR build + weight prep ----
  hipMemsetAsync(cnt, 0, (size_t)N * 4, stream);
  hist_k<<<2048, 256, 0, stream>>>(edst, cnt, E);
  prepW_k<<<96, 256, 0, stream>>>(W0, convW, W1, Wtg);
  scanA_k<<<nbScan, 256, 0, stream>>>(cnt, bsum, N);
  scanB_k<<<1, 128, 0, stream>>>(bsum, bbase, nbScan);
  scanC_k<<<nbScan, 256, 0, stream>>>(cnt, bbase, rp, N, E);
  scatter_k<<<2048, 256, 0, stream>>>(esrc, edst, ew, rp, cnt, epk, E);

  int gemmBlocks = (N + 127) / 128;
  int spmmBlocks = (N + 15) / 16;   // one node per 16-lane group

  // ---- input projection: h = relu(x@W0 + b0) -> hbf, x0bf (bf16) ----
  gemm_mfma<0, 0><<<gemmBlocks, 256, 0, stream>>>(x, Wtg, b0, nullptr, hbf, x0bf, 0.f, 1.f, N);

  // ---- 4 GCNII layers ----
  for (int l = 0; l < 4; ++l) {
    float beta = logf(0.5f / (float)(l + 1) + 1.f);
    spmm_k<<<spmmBlocks, 256, 0, stream>>>(rp, epk, hbf, x0bf, bufB, N);
    gemm_mfma<1, 1><<<gemmBlocks, 256, 0, stream>>>(
        bufB, Wtg + (size_t)(1 + l) * 128 * 128, nullptr,
        nullptr, (l == 3) ? bufA : hbf, nullptr,
        1.f - beta, beta, N);
  }

  // ---- final: logits + log_softmax ----
  gemm_mfma<2, 1><<<gemmBlocks, 256, 0, stream>>>(bufA, Wtg + (size_t)5 * 128 * 128, b1, outp, nullptr, nullptr, 0.f, 1.f, N);
}

// Round 13
// 538.052 us; speedup vs baseline: 1.1458x; 1.1458x over previous
//
#include <hip/hip_runtime.h>
#include <math.h>

typedef unsigned int uint;
typedef unsigned short ushort;
typedef unsigned char uchar;
using bf8   = __attribute__((ext_vector_type(8))) short;   // 8 bf16 (4 VGPRs)
using f32x4 = __attribute__((ext_vector_type(4))) float;   // 4 fp32
using f32x2 = __attribute__((ext_vector_type(2))) float;

__device__ inline ushort f2bf(float f) {
  uint u = __float_as_uint(f);
  return (ushort)((u + 0x7fffu + ((u >> 16) & 1u)) >> 16);
}
__device__ inline float bf2f(ushort s) { return __uint_as_float(((uint)s) << 16); }
__device__ inline uint packbf2(float a, float b) {
  uint ua = __float_as_uint(a), ub = __float_as_uint(b);
  ua = (ua + 0x7fffu + ((ua >> 16) & 1u)) >> 16;
  ub = (ub + 0x7fffu + ((ub >> 16) & 1u)) & 0xffff0000u;
  return ua | ub;
}
__device__ inline float bflo(uint u) { return __uint_as_float(u << 16); }
__device__ inline float bfhi(uint u) { return __uint_as_float(u & 0xffff0000u); }

// ---- fp8 e4m3 conversions (gather table only; values are post-ReLU >= 0) ----
// Word-select must be an immediate -> template parameter.
#if __has_builtin(__builtin_amdgcn_cvt_pk_f32_fp8)
template<bool W>
__device__ inline f32x2 fp8x2_f32(uint v) {
  return __builtin_amdgcn_cvt_pk_f32_fp8((int)v, W);
}
#else
__device__ inline float fp8_1(uint b) {
  uint e = (b >> 3) & 15u, m = b & 7u;
  float nrm = __uint_as_float(((e + 120u) << 23) | (m << 20));
  float sub = (float)m * 0.001953125f;
  return e ? nrm : sub;
}
template<bool W>
__device__ inline f32x2 fp8x2_f32(uint v) {
  uint sh = W ? 16u : 0u;
  f32x2 r; r.x = fp8_1((v >> sh) & 0xffu); r.y = fp8_1((v >> (sh + 8)) & 0xffu);
  return r;
}
#endif

__device__ inline uint f32_fp8(float f) {   // f >= 0, round-nearest
  if (!(f > 0.f)) return 0u;
  if (f >= 446.f) return 0x7eu;
  if (f < 0.015625f) return (uint)(f * 512.f + 0.5f);   // subnormal e4m3
  uint u = __float_as_uint(f);
  uint r = u + 0x7ffffu + ((u >> 20) & 1u);
  uint eb = r >> 23, mant = (r >> 20) & 7u;
  if (eb > 135u || (eb == 135u && mant == 7u)) return 0x7eu;
  return ((eb - 120u) << 3) | mant;
}

// ---------------- CSR build ----------------
__global__ void hist_k(const int* __restrict__ dst, int* __restrict__ cnt, int E) {
  int tid = blockIdx.x * blockDim.x + threadIdx.x;
  int stride4 = gridDim.x * blockDim.x * 4;
  for (int base = tid * 4; base + 3 < E; base += stride4) {
    int4 d = *(const int4*)&dst[base];
    atomicAdd(&cnt[d.x], 1);
    atomicAdd(&cnt[d.y], 1);
    atomicAdd(&cnt[d.z], 1);
    atomicAdd(&cnt[d.w], 1);
  }
  int tail0 = (E & ~3);
  int e = tail0 + tid;
  if (e < E) atomicAdd(&cnt[dst[e]], 1);
}

__global__ __launch_bounds__(256) void scanA_k(const int* __restrict__ cnt,
                                               int* __restrict__ bsum, int N) {
  __shared__ int red[256];
  int tid = threadIdx.x;
  int i0 = blockIdx.x * 1024 + tid * 4;
  int s = 0;
  #pragma unroll
  for (int k = 0; k < 4; ++k) { int i = i0 + k; if (i < N) s += cnt[i]; }
  red[tid] = s;
  __syncthreads();
  for (int off = 128; off; off >>= 1) {
    if (tid < off) red[tid] += red[tid + off];
    __syncthreads();
  }
  if (tid == 0) bsum[blockIdx.x] = red[0];
}

__global__ __launch_bounds__(128) void scanB_k(const int* __restrict__ bsum,
                                               int* __restrict__ bbase, int nb) {
  __shared__ int buf[2][128];
  int tid = threadIdx.x;
  buf[0][tid] = (tid < nb) ? bsum[tid] : 0;
  __syncthreads();
  int pin = 0;
  for (int off = 1; off < 128; off <<= 1) {
    int x = buf[pin][tid];
    if (tid >= off) x += buf[pin][tid - off];
    buf[1 - pin][tid] = x;
    __syncthreads();
    pin = 1 - pin;
  }
  if (tid < nb) bbase[tid] = (tid == 0) ? 0 : buf[pin][tid - 1];
}

__global__ __launch_bounds__(256) void scanC_k(const int* __restrict__ cnt,
    const int* __restrict__ bbase, int* __restrict__ rp, int N, int E) {
  __shared__ int buf[2][256];
  int tid = threadIdx.x;
  int i0 = blockIdx.x * 1024 + tid * 4;
  int c[4]; int s = 0;
  #pragma unroll
  for (int k = 0; k < 4; ++k) { int i = i0 + k; c[k] = (i < N) ? cnt[i] : 0; s += c[k]; }
  buf[0][tid] = s;
  __syncthreads();
  int pin = 0;
  for (int off = 1; off < 256; off <<= 1) {
    int x = buf[pin][tid];
    if (tid >= off) x += buf[pin][tid - off];
    buf[1 - pin][tid] = x;
    __syncthreads();
    pin = 1 - pin;
  }
  int run = bbase[blockIdx.x] + buf[pin][tid] - s;
  #pragma unroll
  for (int k = 0; k < 4; ++k) {
    int i = i0 + k;
    if (i < N) { rp[i] = run; run += c[k]; }
  }
  if (blockIdx.x == 0 && tid == 0) rp[N] = E;
}

// scatter into per-node CSR slots; consumes hist counts via atomic decrement.
// Packed 4B record: src (17b, <<15) | w as 15-bit fixed point (quant err 3e-5).
__global__ void scatter_k(const int* __restrict__ src, const int* __restrict__ dst,
                          const float* __restrict__ w, const int* __restrict__ rp,
                          int* __restrict__ cnt, uint* __restrict__ epk, int E) {
  int stride = gridDim.x * blockDim.x;
  for (int e = blockIdx.x * blockDim.x + threadIdx.x; e < E; e += stride) {
    int d = dst[e];
    int off = atomicAdd(&cnt[d], -1) - 1;
    uint wq = (uint)(w[e] * 32767.f + 0.5f);
    epk[rp[d] + off] = ((uint)src[e] << 15) | wq;
  }
}

// ---- prep: transpose + bf16-convert all 6 weight matrices to Wt[m][n][k] ----
__global__ __launch_bounds__(256) void prepW_k(const float* __restrict__ W0,
    const float* __restrict__ convW, const float* __restrict__ W1,
    ushort* __restrict__ Wt) {
  int b = blockIdx.x;
  int m = b >> 4;
  int n0 = (b & 15) * 8;
  const float* W = (m == 0) ? W0 : (m <= 4) ? (convW + (size_t)(m - 1) * 128 * 128) : W1;
  ushort* dst = Wt + (size_t)m * 128 * 128;
  int t = threadIdx.x;
  int n = n0 + (t >> 5);
  int k0 = (t & 31) * 4;
  float a = W[(size_t)(k0 + 0) * 128 + n];
  float c = W[(size_t)(k0 + 1) * 128 + n];
  float d = W[(size_t)(k0 + 2) * 128 + n];
  float e = W[(size_t)(k0 + 3) * 128 + n];
  *(uint2*)&dst[(size_t)n * 128 + k0] = make_uint2(packbf2(a, c), packbf2(d, e));
}

// ---------------- SpMM (pull, CSR by dst, fp8 gather) + initial-residual mix ----------------
// One node per 16-lane group. h table is fp8 e4m3: 128B/row -> 8B (uint2)/lane,
// halving the random-gather line traffic. x0 stays bf16 (anchors accuracy).
__global__ __launch_bounds__(256) void spmm_k(const int* __restrict__ rp,
    const uint* __restrict__ epk, const uchar* __restrict__ h8,
    const ushort* __restrict__ x0bf, ushort* __restrict__ outbf, int N) {
  int node = (blockIdx.x * blockDim.x + threadIdx.x) >> 4;
  int l16 = threadIdx.x & 15;
  if (node >= N) return;
  int b = rp[node], e = rp[node + 1];
  float a0 = 0.f, a1 = 0.f, a2 = 0.f, a3 = 0.f;
  float a4 = 0.f, a5 = 0.f, a6 = 0.f, a7 = 0.f;
  const uint2* hb = (const uint2*)h8;   // 16 uint2 per 128B row
#define EDG(EU, HV) do { \
    float wgt = (float)((EU) & 0x7fffu) * (1.f / 32767.f); \
    f32x2 p0 = fp8x2_f32<false>((HV).x), p1 = fp8x2_f32<true>((HV).x); \
    f32x2 p2 = fp8x2_f32<false>((HV).y), p3 = fp8x2_f32<true>((HV).y); \
    a0 = fmaf(wgt, p0.x, a0); a1 = fmaf(wgt, p0.y, a1); \
    a2 = fmaf(wgt, p1.x, a2); a3 = fmaf(wgt, p1.y, a3); \
    a4 = fmaf(wgt, p2.x, a4); a5 = fmaf(wgt, p2.y, a5); \
    a6 = fmaf(wgt, p3.x, a6); a7 = fmaf(wgt, p3.y, a7); \
  } while (0)
  int j = b;
  for (; j + 7 < e; j += 8) {
    uint u0 = epk[j],     u1 = epk[j + 1], u2 = epk[j + 2], u3 = epk[j + 3];
    uint u4 = epk[j + 4], u5 = epk[j + 5], u6 = epk[j + 6], u7 = epk[j + 7];
    uint2 h0 = hb[(size_t)(u0 >> 15) * 16 + l16];
    uint2 h1 = hb[(size_t)(u1 >> 15) * 16 + l16];
    uint2 h2 = hb[(size_t)(u2 >> 15) * 16 + l16];
    uint2 h3 = hb[(size_t)(u3 >> 15) * 16 + l16];
    uint2 h4 = hb[(size_t)(u4 >> 15) * 16 + l16];
    uint2 h5 = hb[(size_t)(u5 >> 15) * 16 + l16];
    uint2 h6 = hb[(size_t)(u6 >> 15) * 16 + l16];
    uint2 h7 = hb[(size_t)(u7 >> 15) * 16 + l16];
    EDG(u0, h0); EDG(u1, h1); EDG(u2, h2); EDG(u3, h3);
    EDG(u4, h4); EDG(u5, h5); EDG(u6, h6); EDG(u7, h7);
  }
  for (; j + 3 < e; j += 4) {
    uint u0 = epk[j], u1 = epk[j + 1], u2 = epk[j + 2], u3 = epk[j + 3];
    uint2 h0 = hb[(size_t)(u0 >> 15) * 16 + l16];
    uint2 h1 = hb[(size_t)(u1 >> 15) * 16 + l16];
    uint2 h2 = hb[(size_t)(u2 >> 15) * 16 + l16];
    uint2 h3 = hb[(size_t)(u3 >> 15) * 16 + l16];
    EDG(u0, h0); EDG(u1, h1); EDG(u2, h2); EDG(u3, h3);
  }
  for (; j < e; ++j) {
    uint u0 = epk[j];
    uint2 h0 = hb[(size_t)(u0 >> 15) * 16 + l16];
    EDG(u0, h0);
  }
#undef EDG
  uint4 xv = ((const uint4*)x0bf)[(size_t)node * 16 + l16];
  float o0 = 0.9f * a0 + 0.1f * bflo(xv.x);
  float o1 = 0.9f * a1 + 0.1f * bfhi(xv.x);
  float o2 = 0.9f * a2 + 0.1f * bflo(xv.y);
  float o3 = 0.9f * a3 + 0.1f * bfhi(xv.y);
  float o4 = 0.9f * a4 + 0.1f * bflo(xv.z);
  float o5 = 0.9f * a5 + 0.1f * bfhi(xv.z);
  float o6 = 0.9f * a6 + 0.1f * bflo(xv.w);
  float o7 = 0.9f * a7 + 0.1f * bfhi(xv.w);
  uint4 u;
  u.x = packbf2(o0, o1); u.y = packbf2(o2, o3);
  u.z = packbf2(o4, o5); u.w = packbf2(o6, o7);
  ((uint4*)outbf)[(size_t)node * 16 + l16] = u;
}

// ---------------- MFMA dense GEMM, LDS-free ----------------
// A and B fragments direct from global; B = Wt bf16 [n][k] (L1/L2-resident).
// D layout: col = lane&15, row = 4*(lane>>4) + reg.
// MODE 0 (proj, ABF=0, OUT8=1): y = relu(in@W + bias); fp8 -> out8 (h), bf16 -> outbf2 (x0)
// MODE 1 (conv, ABF=1): y = relu(cin*in + cw*(in@W)); OUT8? fp8 h : bf16 outbf
// MODE 2 (final,ABF=1, OUT8=0): y = log_softmax(in@W + bias); f32 -> outf
template<int MODE, int ABF, int OUT8>
__global__ __launch_bounds__(256, 4) void gemm_mfma(const void* __restrict__ inv,
    const ushort* __restrict__ Wt, const float* __restrict__ bias,
    float* __restrict__ outf, ushort* __restrict__ outbf, ushort* __restrict__ outbf2,
    uchar* __restrict__ out8, float cin, float cw, int N) {
  const float*  inf = (const float*)inv;
  const ushort* inb = (const ushort*)inv;
  int tid = threadIdx.x;
  int w = tid >> 6, lane = tid & 63;
  int l15 = lane & 15, hi = lane >> 4;
  int rbase = blockIdx.x * 128 + w * 32;

  f32x4 acc[2][8];
  #pragma unroll
  for (int mi = 0; mi < 2; ++mi)
    #pragma unroll
    for (int ni = 0; ni < 8; ++ni)
      acc[mi][ni] = (f32x4){0.f, 0.f, 0.f, 0.f};

  int r0 = min(rbase + l15, N - 1);
  int r1 = min(rbase + 16 + l15, N - 1);

  #pragma unroll
  for (int kt = 0; kt < 4; ++kt) {
    int koff = kt * 32 + hi * 8;
    bf8 a0, a1;
    if (ABF) {
      a0 = *(const bf8*)&inb[(size_t)r0 * 128 + koff];
      a1 = *(const bf8*)&inb[(size_t)r1 * 128 + koff];
    } else {
      float4 f0 = *(const float4*)&inf[(size_t)r0 * 128 + koff];
      float4 f1 = *(const float4*)&inf[(size_t)r0 * 128 + koff + 4];
      float4 g0 = *(const float4*)&inf[(size_t)r1 * 128 + koff];
      float4 g1 = *(const float4*)&inf[(size_t)r1 * 128 + koff + 4];
      union { bf8 v; uint u[4]; } ta, tb;
      ta.u[0] = packbf2(f0.x, f0.y); ta.u[1] = packbf2(f0.z, f0.w);
      ta.u[2] = packbf2(f1.x, f1.y); ta.u[3] = packbf2(f1.z, f1.w);
      tb.u[0] = packbf2(g0.x, g0.y); tb.u[1] = packbf2(g0.z, g0.w);
      tb.u[2] = packbf2(g1.x, g1.y); tb.u[3] = packbf2(g1.z, g1.w);
      a0 = ta.v; a1 = tb.v;
    }
    #pragma unroll
    for (int ni = 0; ni < 8; ++ni) {
      bf8 b = *(const bf8*)&Wt[(size_t)(ni * 16 + l15) * 128 + koff];
      acc[0][ni] = __builtin_amdgcn_mfma_f32_16x16x32_bf16(a0, b, acc[0][ni], 0, 0, 0);
      acc[1][ni] = __builtin_amdgcn_mfma_f32_16x16x32_bf16(a1, b, acc[1][ni], 0, 0, 0);
    }
  }

  float bcol[8];
  if (MODE != 1) {
    #pragma unroll
    for (int ni = 0; ni < 8; ++ni) bcol[ni] = bias[ni * 16 + l15];
  }

  #pragma unroll
  for (int mi = 0; mi < 2; ++mi) {
    #pragma unroll
    for (int reg = 0; reg < 4; ++reg) {
      int row = rbase + mi * 16 + 4 * hi + reg;
      bool valid = (row < N);
      float y[8];
      #pragma unroll
      for (int ni = 0; ni < 8; ++ni) y[ni] = acc[mi][ni][reg];
      if (MODE == 1) {
        if (valid) {
          #pragma unroll
          for (int ni = 0; ni < 8; ++ni) {
            float iv = bf2f(inb[(size_t)row * 128 + ni * 16 + l15]);
            y[ni] = fmaxf(cin * iv + cw * y[ni], 0.f);
          }
        }
      } else {
        #pragma unroll
        for (int ni = 0; ni < 8; ++ni) y[ni] += bcol[ni];
        if (MODE == 0) {
          #pragma unroll
          for (int ni = 0; ni < 8; ++ni) y[ni] = fmaxf(y[ni], 0.f);
        }
      }
      if (MODE == 2) {
        float m = y[0];
        #pragma unroll
        for (int ni = 1; ni < 8; ++ni) m = fmaxf(m, y[ni]);
        #pragma unroll
        for (int off = 1; off <= 8; off <<= 1) m = fmaxf(m, __shfl_xor(m, off));
        float s = 0.f;
        #pragma unroll
        for (int ni = 0; ni < 8; ++ni) s += expf(y[ni] - m);
        #pragma unroll
        for (int off = 1; off <= 8; off <<= 1) s += __shfl_xor(s, off);
        float lg = m + logf(s);
        #pragma unroll
        for (int ni = 0; ni < 8; ++ni) y[ni] -= lg;
      }
      if (valid) {
        if (MODE == 2) {
          #pragma unroll
          for (int ni = 0; ni < 8; ++ni)
            outf[(size_t)row * 128 + ni * 16 + l15] = y[ni];
        } else {
          #pragma unroll
          for (int ni = 0; ni < 8; ++ni) {
            size_t idx = (size_t)row * 128 + ni * 16 + l15;
            if (OUT8) out8[idx] = (uchar)f32_fp8(y[ni]);
            else      outbf[idx] = f2bf(y[ni]);
            if (MODE == 0) outbf2[idx] = f2bf(y[ni]);
          }
        }
      }
    }
  }
}

extern "C" void kernel_launch(void* const* d_in, const int* in_sizes, int n_in,
                              void* d_out, int out_size, void* d_ws, size_t ws_size,
                              hipStream_t stream) {
  const float* x     = (const float*)d_in[0];
  const int*   esrc  = (const int*)d_in[1];
  const int*   edst  = (const int*)d_in[2];
  const float* ew    = (const float*)d_in[3];
  const float* W0    = (const float*)d_in[4];
  const float* b0    = (const float*)d_in[5];
  const float* W1    = (const float*)d_in[6];
  const float* b1    = (const float*)d_in[7];
  const float* convW = (const float*)d_in[8];
  int N = in_sizes[0] / 128;
  int E = in_sizes[1];
  float* outp = (float*)d_out;

  char* ws = (char*)d_ws;
  size_t off = 0;
  auto alloc = [&](size_t bytes) {
    void* p = ws + off;
    off += (bytes + 255) & ~(size_t)255;
    return p;
  };
  uchar*  h8    = (uchar*)alloc((size_t)N * 128);        // fp8 gather table
  ushort* x0bf  = (ushort*)alloc((size_t)N * 128 * 2);
  ushort* bufB  = (ushort*)alloc((size_t)N * 128 * 2);   // spmm out (bf16)
  ushort* bufA  = (ushort*)alloc((size_t)N * 128 * 2);   // final-GEMM input (bf16)
  ushort* Wtg   = (ushort*)alloc((size_t)6 * 128 * 128 * 2);
  int*    rp    = (int*)alloc((size_t)(N + 1) * 4);
  int*    cnt   = (int*)alloc((size_t)N * 4);
  uint*   epk   = (uint*)alloc((size_t)E * 4);
  int nbScan = (N + 1023) / 1024;
  int*    bsum  = (int*)alloc((size_t)nbScan * 4);
  int*    bbase = (int*)alloc((size_t)nbScan * 4);

  // ---- CSR build + weight prep ----
  (void)hipMemsetAsync(cnt, 0, (size_t)N * 4, stream);
  hist_k<<<2048, 256, 0, stream>>>(edst, cnt, E);
  prepW_k<<<96, 256, 0, stream>>>(W0, convW, W1, Wtg);
  scanA_k<<<nbScan, 256, 0, stream>>>(cnt, bsum, N);
  scanB_k<<<1, 128, 0, stream>>>(bsum, bbase, nbScan);
  scanC_k<<<nbScan, 256, 0, stream>>>(cnt, bbase, rp, N, E);
  scatter_k<<<2048, 256, 0, stream>>>(esrc, edst, ew, rp, cnt, epk, E);

  int gemmBlocks = (N + 127) / 128;
  int spmmBlocks = (N + 15) / 16;   // one node per 16-lane group

  // ---- input projection: h = relu(x@W0 + b0) -> h8 (fp8), x0bf (bf16) ----
  gemm_mfma<0, 0, 1><<<gemmBlocks, 256, 0, stream>>>(
      x, Wtg, b0, nullptr, nullptr, x0bf, h8, 0.f, 1.f, N);

  // ---- 4 GCNII layers ----
  for (int l = 0; l < 4; ++l) {
    float beta = logf(0.5f / (float)(l + 1) + 1.f);
    spmm_k<<<spmmBlocks, 256, 0, stream>>>(rp, epk, h8, x0bf, bufB, N);
    if (l < 3) {
      gemm_mfma<1, 1, 1><<<gemmBlocks, 256, 0, stream>>>(
          bufB, Wtg + (size_t)(1 + l) * 128 * 128, nullptr,
          nullptr, nullptr, nullptr, h8, 1.f - beta, beta, N);
    } else {
      gemm_mfma<1, 1, 0><<<gemmBlocks, 256, 0, stream>>>(
          bufB, Wtg + (size_t)(1 + l) * 128 * 128, nullptr,
          nullptr, bufA, nullptr, nullptr, 1.f - beta, beta, N);
    }
  }

  // ---- final: logits + log_softmax ----
  gemm_mfma<2, 1, 0><<<gemmBlocks, 256, 0, stream>>>(
      bufA, Wtg + (size_t)5 * 128 * 128, b1, outp, nullptr, nullptr, nullptr, 0.f, 1.f, N);
}

// Round 15
// 495.445 us; speedup vs baseline: 1.2443x; 1.0860x over previous
//
#include <hip/hip_runtime.h>
#include <math.h>

typedef unsigned int uint;
typedef unsigned short ushort;
typedef unsigned char uchar;
using bf8   = __attribute__((ext_vector_type(8))) short;   // 8 bf16 (4 VGPRs)
using f32x4 = __attribute__((ext_vector_type(4))) float;   // 4 fp32
using f32x2 = __attribute__((ext_vector_type(2))) float;

__device__ inline ushort f2bf(float f) {
  uint u = __float_as_uint(f);
  return (ushort)((u + 0x7fffu + ((u >> 16) & 1u)) >> 16);
}
__device__ inline float bf2f(ushort s) { return __uint_as_float(((uint)s) << 16); }
__device__ inline uint packbf2(float a, float b) {
  uint ua = __float_as_uint(a), ub = __float_as_uint(b);
  ua = (ua + 0x7fffu + ((ua >> 16) & 1u)) >> 16;
  ub = (ub + 0x7fffu + ((ub >> 16) & 1u)) & 0xffff0000u;
  return ua | ub;
}
__device__ inline float bflo(uint u) { return __uint_as_float(u << 16); }
__device__ inline float bfhi(uint u) { return __uint_as_float(u & 0xffff0000u); }

// ---- fp8 e4m3 conversions (gather table only; values are post-ReLU >= 0) ----
#if __has_builtin(__builtin_amdgcn_cvt_pk_f32_fp8)
template<bool W>
__device__ inline f32x2 fp8x2_f32(uint v) {
  return __builtin_amdgcn_cvt_pk_f32_fp8((int)v, W);
}
#else
__device__ inline float fp8_1(uint b) {
  uint e = (b >> 3) & 15u, m = b & 7u;
  float nrm = __uint_as_float(((e + 120u) << 23) | (m << 20));
  float sub = (float)m * 0.001953125f;
  return e ? nrm : sub;
}
template<bool W>
__device__ inline f32x2 fp8x2_f32(uint v) {
  uint sh = W ? 16u : 0u;
  f32x2 r; r.x = fp8_1((v >> sh) & 0xffu); r.y = fp8_1((v >> (sh + 8)) & 0xffu);
  return r;
}
#endif

__device__ inline uint f32_fp8(float f) {   // f >= 0, round-nearest
  if (!(f > 0.f)) return 0u;
  if (f >= 446.f) return 0x7eu;
  if (f < 0.015625f) return (uint)(f * 512.f + 0.5f);   // subnormal e4m3
  uint u = __float_as_uint(f);
  uint r = u + 0x7ffffu + ((u >> 20) & 1u);
  uint eb = r >> 23, mant = (r >> 20) & 7u;
  if (eb > 135u || (eb == 135u && mant == 7u)) return 0x7eu;
  return ((eb - 120u) << 3) | mant;
}

// ---------------- CSR build ----------------
__global__ void hist_k(const int* __restrict__ dst, int* __restrict__ cnt, int E) {
  int tid = blockIdx.x * blockDim.x + threadIdx.x;
  int stride4 = gridDim.x * blockDim.x * 4;
  for (int base = tid * 4; base + 3 < E; base += stride4) {
    int4 d = *(const int4*)&dst[base];
    atomicAdd(&cnt[d.x], 1);
    atomicAdd(&cnt[d.y], 1);
    atomicAdd(&cnt[d.z], 1);
    atomicAdd(&cnt[d.w], 1);
  }
  int tail0 = (E & ~3);
  int e = tail0 + tid;
  if (e < E) atomicAdd(&cnt[dst[e]], 1);
}

__global__ __launch_bounds__(256) void scanA_k(const int* __restrict__ cnt,
                                               int* __restrict__ bsum, int N) {
  __shared__ int red[256];
  int tid = threadIdx.x;
  int i0 = blockIdx.x * 1024 + tid * 4;
  int s = 0;
  #pragma unroll
  for (int k = 0; k < 4; ++k) { int i = i0 + k; if (i < N) s += cnt[i]; }
  red[tid] = s;
  __syncthreads();
  for (int off = 128; off; off >>= 1) {
    if (tid < off) red[tid] += red[tid + off];
    __syncthreads();
  }
  if (tid == 0) bsum[blockIdx.x] = red[0];
}

__global__ __launch_bounds__(128) void scanB_k(const int* __restrict__ bsum,
                                               int* __restrict__ bbase, int nb) {
  __shared__ int buf[2][128];
  int tid = threadIdx.x;
  buf[0][tid] = (tid < nb) ? bsum[tid] : 0;
  __syncthreads();
  int pin = 0;
  for (int off = 1; off < 128; off <<= 1) {
    int x = buf[pin][tid];
    if (tid >= off) x += buf[pin][tid - off];
    buf[1 - pin][tid] = x;
    __syncthreads();
    pin = 1 - pin;
  }
  if (tid < nb) bbase[tid] = (tid == 0) ? 0 : buf[pin][tid - 1];
}

__global__ __launch_bounds__(256) void scanC_k(const int* __restrict__ cnt,
    const int* __restrict__ bbase, int* __restrict__ rp, int N, int E) {
  __shared__ int buf[2][256];
  int tid = threadIdx.x;
  int i0 = blockIdx.x * 1024 + tid * 4;
  int c[4]; int s = 0;
  #pragma unroll
  for (int k = 0; k < 4; ++k) { int i = i0 + k; c[k] = (i < N) ? cnt[i] : 0; s += c[k]; }
  buf[0][tid] = s;
  __syncthreads();
  int pin = 0;
  for (int off = 1; off < 256; off <<= 1) {
    int x = buf[pin][tid];
    if (tid >= off) x += buf[pin][tid - off];
    buf[1 - pin][tid] = x;
    __syncthreads();
    pin = 1 - pin;
  }
  int run = bbase[blockIdx.x] + buf[pin][tid] - s;
  #pragma unroll
  for (int k = 0; k < 4; ++k) {
    int i = i0 + k;
    if (i < N) { rp[i] = run; run += c[k]; }
  }
  if (blockIdx.x == 0 && tid == 0) rp[N] = E;
}

// XCD-partitioned scatter: block b -> partition p = b&7 (assumes round-robin
// blockIdx->XCD; perf heuristic only, correctness independent). Blocks with
// partition p write ONLY nodes [p*nper, (p+1)*nper): all ~16 writes to a
// 64B CSR line come from one XCD's L2 -> line accumulates locally, single
// writeback (vs cross-XCD ping-pong = 64B/record observed in R13).
// Cost: dst re-read x8 (L3-resident); src/w read once per edge.
__global__ __launch_bounds__(256) void scatter_k(const int* __restrict__ src,
    const int* __restrict__ dst, const float* __restrict__ w,
    const int* __restrict__ rp, int* __restrict__ cnt,
    uint* __restrict__ epk, int E, int N) {
  int part = blockIdx.x & 7;
  int slice = blockIdx.x >> 3;
  int nslices = gridDim.x >> 3;
  int per = (E + nslices - 1) / nslices;
  int lo = slice * per, hi = min(E, lo + per);
  int nper = (N + 7) >> 3;
  int nlo = part * nper, nhi = min(N, nlo + nper);
  for (int e = lo + threadIdx.x; e < hi; e += 256) {
    int d = dst[e];
    if (d < nlo || d >= nhi) continue;
    int off = atomicAdd(&cnt[d], -1) - 1;
    uint wq = (uint)(w[e] * 32767.f + 0.5f);
    epk[rp[d] + off] = ((uint)src[e] << 15) | wq;
  }
}

// ---- prep: transpose + bf16-convert all 6 weight matrices to Wt[m][n][k] ----
__global__ __launch_bounds__(256) void prepW_k(const float* __restrict__ W0,
    const float* __restrict__ convW, const float* __restrict__ W1,
    ushort* __restrict__ Wt) {
  int b = blockIdx.x;
  int m = b >> 4;
  int n0 = (b & 15) * 8;
  const float* W = (m == 0) ? W0 : (m <= 4) ? (convW + (size_t)(m - 1) * 128 * 128) : W1;
  ushort* dst = Wt + (size_t)m * 128 * 128;
  int t = threadIdx.x;
  int n = n0 + (t >> 5);
  int k0 = (t & 31) * 4;
  float a = W[(size_t)(k0 + 0) * 128 + n];
  float c = W[(size_t)(k0 + 1) * 128 + n];
  float d = W[(size_t)(k0 + 2) * 128 + n];
  float e = W[(size_t)(k0 + 3) * 128 + n];
  *(uint2*)&dst[(size_t)n * 128 + k0] = make_uint2(packbf2(a, c), packbf2(d, e));
}

// ---------------- SpMM (pull, CSR by dst, fp8 gather) + initial-residual mix ----------------
__global__ __launch_bounds__(256) void spmm_k(const int* __restrict__ rp,
    const uint* __restrict__ epk, const uchar* __restrict__ h8,
    const ushort* __restrict__ x0bf, ushort* __restrict__ outbf, int N) {
  int node = (blockIdx.x * blockDim.x + threadIdx.x) >> 4;
  int l16 = threadIdx.x & 15;
  if (node >= N) return;
  int b = rp[node], e = rp[node + 1];
  float a0 = 0.f, a1 = 0.f, a2 = 0.f, a3 = 0.f;
  float a4 = 0.f, a5 = 0.f, a6 = 0.f, a7 = 0.f;
  const uint2* hb = (const uint2*)h8;   // 16 uint2 per 128B row
#define EDG(EU, HV) do { \
    float wgt = (float)((EU) & 0x7fffu) * (1.f / 32767.f); \
    f32x2 p0 = fp8x2_f32<false>((HV).x), p1 = fp8x2_f32<true>((HV).x); \
    f32x2 p2 = fp8x2_f32<false>((HV).y), p3 = fp8x2_f32<true>((HV).y); \
    a0 = fmaf(wgt, p0.x, a0); a1 = fmaf(wgt, p0.y, a1); \
    a2 = fmaf(wgt, p1.x, a2); a3 = fmaf(wgt, p1.y, a3); \
    a4 = fmaf(wgt, p2.x, a4); a5 = fmaf(wgt, p2.y, a5); \
    a6 = fmaf(wgt, p3.x, a6); a7 = fmaf(wgt, p3.y, a7); \
  } while (0)
  int j = b;
  for (; j + 7 < e; j += 8) {
    uint u0 = epk[j],     u1 = epk[j + 1], u2 = epk[j + 2], u3 = epk[j + 3];
    uint u4 = epk[j + 4], u5 = epk[j + 5], u6 = epk[j + 6], u7 = epk[j + 7];
    uint2 h0 = hb[(size_t)(u0 >> 15) * 16 + l16];
    uint2 h1 = hb[(size_t)(u1 >> 15) * 16 + l16];
    uint2 h2 = hb[(size_t)(u2 >> 15) * 16 + l16];
    uint2 h3 = hb[(size_t)(u3 >> 15) * 16 + l16];
    uint2 h4 = hb[(size_t)(u4 >> 15) * 16 + l16];
    uint2 h5 = hb[(size_t)(u5 >> 15) * 16 + l16];
    uint2 h6 = hb[(size_t)(u6 >> 15) * 16 + l16];
    uint2 h7 = hb[(size_t)(u7 >> 15) * 16 + l16];
    EDG(u0, h0); EDG(u1, h1); EDG(u2, h2); EDG(u3, h3);
    EDG(u4, h4); EDG(u5, h5); EDG(u6, h6); EDG(u7, h7);
  }
  for (; j + 3 < e; j += 4) {
    uint u0 = epk[j], u1 = epk[j + 1], u2 = epk[j + 2], u3 = epk[j + 3];
    uint2 h0 = hb[(size_t)(u0 >> 15) * 16 + l16];
    uint2 h1 = hb[(size_t)(u1 >> 15) * 16 + l16];
    uint2 h2 = hb[(size_t)(u2 >> 15) * 16 + l16];
    uint2 h3 = hb[(size_t)(u3 >> 15) * 16 + l16];
    EDG(u0, h0); EDG(u1, h1); EDG(u2, h2); EDG(u3, h3);
  }
  for (; j < e; ++j) {
    uint u0 = epk[j];
    uint2 h0 = hb[(size_t)(u0 >> 15) * 16 + l16];
    EDG(u0, h0);
  }
#undef EDG
  uint4 xv = ((const uint4*)x0bf)[(size_t)node * 16 + l16];
  float o0 = 0.9f * a0 + 0.1f * bflo(xv.x);
  float o1 = 0.9f * a1 + 0.1f * bfhi(xv.x);
  float o2 = 0.9f * a2 + 0.1f * bflo(xv.y);
  float o3 = 0.9f * a3 + 0.1f * bfhi(xv.y);
  float o4 = 0.9f * a4 + 0.1f * bflo(xv.z);
  float o5 = 0.9f * a5 + 0.1f * bfhi(xv.z);
  float o6 = 0.9f * a6 + 0.1f * bflo(xv.w);
  float o7 = 0.9f * a7 + 0.1f * bfhi(xv.w);
  uint4 u;
  u.x = packbf2(o0, o1); u.y = packbf2(o2, o3);
  u.z = packbf2(o4, o5); u.w = packbf2(o6, o7);
  ((uint4*)outbf)[(size_t)node * 16 + l16] = u;
}

// ---------------- MFMA dense GEMM, LDS-free ----------------
// MODE 0 (proj, ABF=0, OUT8=1): y = relu(in@W + bias); fp8 -> out8 (h), bf16 -> outbf2 (x0)
// MODE 1 (conv, ABF=1): y = relu(cin*in + cw*(in@W)); OUT8? fp8 h : bf16 outbf
// MODE 2 (final,ABF=1, OUT8=0): y = log_softmax(in@W + bias); f32 -> outf
template<int MODE, int ABF, int OUT8>
__global__ __launch_bounds__(256, 4) void gemm_mfma(const void* __restrict__ inv,
    const ushort* __restrict__ Wt, const float* __restrict__ bias,
    float* __restrict__ outf, ushort* __restrict__ outbf, ushort* __restrict__ outbf2,
    uchar* __restrict__ out8, float cin, float cw, int N) {
  const float*  inf = (const float*)inv;
  const ushort* inb = (const ushort*)inv;
  int tid = threadIdx.x;
  int w = tid >> 6, lane = tid & 63;
  int l15 = lane & 15, hi = lane >> 4;
  int rbase = blockIdx.x * 128 + w * 32;

  f32x4 acc[2][8];
  #pragma unroll
  for (int mi = 0; mi < 2; ++mi)
    #pragma unroll
    for (int ni = 0; ni < 8; ++ni)
      acc[mi][ni] = (f32x4){0.f, 0.f, 0.f, 0.f};

  int r0 = min(rbase + l15, N - 1);
  int r1 = min(rbase + 16 + l15, N - 1);

  #pragma unroll
  for (int kt = 0; kt < 4; ++kt) {
    int koff = kt * 32 + hi * 8;
    bf8 a0, a1;
    if (ABF) {
      a0 = *(const bf8*)&inb[(size_t)r0 * 128 + koff];
      a1 = *(const bf8*)&inb[(size_t)r1 * 128 + koff];
    } else {
      float4 f0 = *(const float4*)&inf[(size_t)r0 * 128 + koff];
      float4 f1 = *(const float4*)&inf[(size_t)r0 * 128 + koff + 4];
      float4 g0 = *(const float4*)&inf[(size_t)r1 * 128 + koff];
      float4 g1 = *(const float4*)&inf[(size_t)r1 * 128 + koff + 4];
      union { bf8 v; uint u[4]; } ta, tb;
      ta.u[0] = packbf2(f0.x, f0.y); ta.u[1] = packbf2(f0.z, f0.w);
      ta.u[2] = packbf2(f1.x, f1.y); ta.u[3] = packbf2(f1.z, f1.w);
      tb.u[0] = packbf2(g0.x, g0.y); tb.u[1] = packbf2(g0.z, g0.w);
      tb.u[2] = packbf2(g1.x, g1.y); tb.u[3] = packbf2(g1.z, g1.w);
      a0 = ta.v; a1 = tb.v;
    }
    #pragma unroll
    for (int ni = 0; ni < 8; ++ni) {
      bf8 b = *(const bf8*)&Wt[(size_t)(ni * 16 + l15) * 128 + koff];
      acc[0][ni] = __builtin_amdgcn_mfma_f32_16x16x32_bf16(a0, b, acc[0][ni], 0, 0, 0);
      acc[1][ni] = __builtin_amdgcn_mfma_f32_16x16x32_bf16(a1, b, acc[1][ni], 0, 0, 0);
    }
  }

  float bcol[8];
  if (MODE != 1) {
    #pragma unroll
    for (int ni = 0; ni < 8; ++ni) bcol[ni] = bias[ni * 16 + l15];
  }

  #pragma unroll
  for (int mi = 0; mi < 2; ++mi) {
    #pragma unroll
    for (int reg = 0; reg < 4; ++reg) {
      int row = rbase + mi * 16 + 4 * hi + reg;
      bool valid = (row < N);
      float y[8];
      #pragma unroll
      for (int ni = 0; ni < 8; ++ni) y[ni] = acc[mi][ni][reg];
      if (MODE == 1) {
        if (valid) {
          #pragma unroll
          for (int ni = 0; ni < 8; ++ni) {
            float iv = bf2f(inb[(size_t)row * 128 + ni * 16 + l15]);
            y[ni] = fmaxf(cin * iv + cw * y[ni], 0.f);
          }
        }
      } else {
        #pragma unroll
        for (int ni = 0; ni < 8; ++ni) y[ni] += bcol[ni];
        if (MODE == 0) {
          #pragma unroll
          for (int ni = 0; ni < 8; ++ni) y[ni] = fmaxf(y[ni], 0.f);
        }
      }
      if (MODE == 2) {
        float m = y[0];
        #pragma unroll
        for (int ni = 1; ni < 8; ++ni) m = fmaxf(m, y[ni]);
        #pragma unroll
        for (int off = 1; off <= 8; off <<= 1) m = fmaxf(m, __shfl_xor(m, off));
        float s = 0.f;
        #pragma unroll
        for (int ni = 0; ni < 8; ++ni) s += expf(y[ni] - m);
        #pragma unroll
        for (int off = 1; off <= 8; off <<= 1) s += __shfl_xor(s, off);
        float lg = m + logf(s);
        #pragma unroll
        for (int ni = 0; ni < 8; ++ni) y[ni] -= lg;
      }
      if (valid) {
        if (MODE == 2) {
          #pragma unroll
          for (int ni = 0; ni < 8; ++ni)
            outf[(size_t)row * 128 + ni * 16 + l15] = y[ni];
        } else {
          #pragma unroll
          for (int ni = 0; ni < 8; ++ni) {
            size_t idx = (size_t)row * 128 + ni * 16 + l15;
            if (OUT8) out8[idx] = (uchar)f32_fp8(y[ni]);
            else      outbf[idx] = f2bf(y[ni]);
            if (MODE == 0) outbf2[idx] = f2bf(y[ni]);
          }
        }
      }
    }
  }
}

extern "C" void kernel_launch(void* const* d_in, const int* in_sizes, int n_in,
                              void* d_out, int out_size, void* d_ws, size_t ws_size,
                              hipStream_t stream) {
  const float* x     = (const float*)d_in[0];
  const int*   esrc  = (const int*)d_in[1];
  const int*   edst  = (const int*)d_in[2];
  const float* ew    = (const float*)d_in[3];
  const float* W0    = (const float*)d_in[4];
  const float* b0    = (const float*)d_in[5];
  const float* W1    = (const float*)d_in[6];
  const float* b1    = (const float*)d_in[7];
  const float* convW = (const float*)d_in[8];
  int N = in_sizes[0] / 128;
  int E = in_sizes[1];
  float* outp = (float*)d_out;

  char* ws = (char*)d_ws;
  size_t off = 0;
  auto alloc = [&](size_t bytes) {
    void* p = ws + off;
    off += (bytes + 255) & ~(size_t)255;
    return p;
  };
  uchar*  h8    = (uchar*)alloc((size_t)N * 128);        // fp8 gather table
  ushort* x0bf  = (ushort*)alloc((size_t)N * 128 * 2);
  ushort* bufB  = (ushort*)alloc((size_t)N * 128 * 2);   // spmm out (bf16)
  ushort* bufA  = (ushort*)alloc((size_t)N * 128 * 2);   // final-GEMM input (bf16)
  ushort* Wtg   = (ushort*)alloc((size_t)6 * 128 * 128 * 2);
  int*    rp    = (int*)alloc((size_t)(N + 1) * 4);
  int*    cnt   = (int*)alloc((size_t)N * 4);
  uint*   epk   = (uint*)alloc((size_t)E * 4);
  int nbScan = (N + 1023) / 1024;
  int*    bsum  = (int*)alloc((size_t)nbScan * 4);
  int*    bbase = (int*)alloc((size_t)nbScan * 4);

  // ---- CSR build + weight prep ----
  (void)hipMemsetAsync(cnt, 0, (size_t)N * 4, stream);
  hist_k<<<2048, 256, 0, stream>>>(edst, cnt, E);
  prepW_k<<<96, 256, 0, stream>>>(W0, convW, W1, Wtg);
  scanA_k<<<nbScan, 256, 0, stream>>>(cnt, bsum, N);
  scanB_k<<<1, 128, 0, stream>>>(bsum, bbase, nbScan);
  scanC_k<<<nbScan, 256, 0, stream>>>(cnt, bbase, rp, N, E);
  scatter_k<<<2048, 256, 0, stream>>>(esrc, edst, ew, rp, cnt, epk, E, N);

  int gemmBlocks = (N + 127) / 128;
  int spmmBlocks = (N + 15) / 16;   // one node per 16-lane group

  // ---- input projection: h = relu(x@W0 + b0) -> h8 (fp8), x0bf (bf16) ----
  gemm_mfma<0, 0, 1><<<gemmBlocks, 256, 0, stream>>>(
      x, Wtg, b0, nullptr, nullptr, x0bf, h8, 0.f, 1.f, N);

  // ---- 4 GCNII layers ----
  for (int l = 0; l < 4; ++l) {
    float beta = logf(0.5f / (float)(l + 1) + 1.f);
    spmm_k<<<spmmBlocks, 256, 0, stream>>>(rp, epk, h8, x0bf, bufB, N);
    if (l < 3) {
      gemm_mfma<1, 1, 1><<<gemmBlocks, 256, 0, stream>>>(
          bufB, Wtg + (size_t)(1 + l) * 128 * 128, nullptr,
          nullptr, nullptr, nullptr, h8, 1.f - beta, beta, N);
    } else {
      gemm_mfma<1, 1, 0><<<gemmBlocks, 256, 0, stream>>>(
          bufB, Wtg + (size_t)(1 + l) * 128 * 128, nullptr,
          nullptr, bufA, nullptr, nullptr, 1.f - beta, beta, N);
    }
  }

  // ---- final: logits + log_softmax ----
  gemm_mfma<2, 1, 0><<<gemmBlocks, 256, 0, stream>>>(
      bufA, Wtg + (size_t)5 * 128 * 128, b1, outp, nullptr, nullptr, nullptr, 0.f, 1.f, N);
}